// Round 1
// baseline (234.787 us; speedup 1.0000x reference)
//
#include <hip/hip_runtime.h>
#include <math.h>

#define T_DIM 4096
#define B_DIM 8
#define C_DIM 1024
#define H_DIM 16
#define K_DIM 31
#define PAD_L 30
#define TILE_T 64
#define BLOCK 256

// One thread per (b,c) column, TILE_T consecutive t per thread.
// cc = b*C + c flat column index; lanes -> consecutive c -> coalesced.
// Each wave (64 lanes) covers exactly one head (R = C/H = 64).
__global__ __launch_bounds__(BLOCK) void lightconv_kernel(
    const float* __restrict__ x,
    const float* __restrict__ w,
    float* __restrict__ out)
{
    __shared__ float s_taps[4][K_DIM];   // 4 heads per 256-thread block

    const int tid    = threadIdx.x;
    const int colBlk = blockIdx.x;       // 0..31  (B*C / BLOCK)
    const int tBlk   = blockIdx.y;       // 0..63  (T / TILE_T)
    const int cc     = colBlk * BLOCK + tid;   // flat b*C + c
    const int t0     = tBlk * TILE_T;

    // ---- per-block softmax of the block's 4 heads (threads 0..3) ----
    if (tid < 4) {
        const int c0 = (colBlk * BLOCK) % C_DIM;   // multiple of 256
        const int h  = (c0 >> 6) + tid;            // head index
        const float* wr = w + h * K_DIM;
        float m = -1e30f;
        #pragma unroll
        for (int k = 0; k < K_DIM; ++k) m = fmaxf(m, wr[k]);
        float s = 0.0f;
        #pragma unroll
        for (int k = 0; k < K_DIM; ++k) {
            float e = __expf(wr[k] - m);
            s_taps[tid][k] = e;
            s += e;
        }
        const float inv = 1.0f / s;
        #pragma unroll
        for (int k = 0; k < K_DIM; ++k) s_taps[tid][k] *= inv;
    }
    __syncthreads();

    // taps are wave-uniform (one head per wave); LDS broadcast reads
    float taps[K_DIM];
    const int hl = tid >> 6;
    #pragma unroll
    for (int k = 0; k < K_DIM; ++k) taps[k] = s_taps[hl][k];

    // ---- load x window [t0-30, t0+63] for this column ----
    const long stride = (long)B_DIM * C_DIM;   // 8192 elems between t's
    float xv[TILE_T + PAD_L];
    #pragma unroll
    for (int j = 0; j < TILE_T + PAD_L; ++j) {
        const int t = t0 + j - PAD_L;
        xv[j] = (t >= 0) ? x[(long)t * stride + cc] : 0.0f;   // only chunk 0 hits t<0
    }

    // ---- compute 64 outputs: out[t0+i] = sum_k taps[k] * x[t0+i-30+k] ----
    #pragma unroll
    for (int i = 0; i < TILE_T; ++i) {
        float acc = 0.0f;
        #pragma unroll
        for (int k = 0; k < K_DIM; ++k)
            acc = fmaf(taps[k], xv[i + k], acc);
        out[(long)(t0 + i) * stride + cc] = acc;
    }
}

extern "C" void kernel_launch(void* const* d_in, const int* in_sizes, int n_in,
                              void* d_out, int out_size, void* d_ws, size_t ws_size,
                              hipStream_t stream) {
    const float* x = (const float*)d_in[0];    // [T, B, C] fp32
    const float* w = (const float*)d_in[1];    // [H, K]    fp32
    float* out = (float*)d_out;                // [T, B, C] fp32

    dim3 grid((B_DIM * C_DIM) / BLOCK, T_DIM / TILE_T);  // (32, 64)
    lightconv_kernel<<<grid, BLOCK, 0, stream>>>(x, w, out);
}